// Round 11
// baseline (235.821 us; speedup 1.0000x reference)
//
#include <hip/hip_runtime.h>
#include <stdint.h>

typedef unsigned short u16;
typedef unsigned int   u32;
typedef __attribute__((ext_vector_type(8))) short short8;
typedef __attribute__((ext_vector_type(4))) float f32x4;

static constexpr int kN = 16384;
static constexpr float kEPS = 1e-5f;

__device__ __forceinline__ u16 f2bf(float x) {
  u32 u = __float_as_uint(x);
  u32 r = (u + 0x7fffu + ((u >> 16) & 1u)) >> 16;
  return (u16)r;
}
__device__ __forceinline__ float bf2f(u16 x) {
  return __uint_as_float(((u32)x) << 16);
}
__device__ __forceinline__ void ldbf8(const u16* p, float* o) {
  uint4 v = *(const uint4*)p;
  o[0] = __uint_as_float(v.x << 16);  o[1] = __uint_as_float(v.x & 0xffff0000u);
  o[2] = __uint_as_float(v.y << 16);  o[3] = __uint_as_float(v.y & 0xffff0000u);
  o[4] = __uint_as_float(v.z << 16);  o[5] = __uint_as_float(v.z & 0xffff0000u);
  o[6] = __uint_as_float(v.w << 16);  o[7] = __uint_as_float(v.w & 0xffff0000u);
}
__device__ __forceinline__ void gll16(const u16* g, u16* l) {
  __builtin_amdgcn_global_load_lds(
      (const __attribute__((address_space(1))) void*)g,
      (__attribute__((address_space(3))) void*)l, 16, 0, 0);
}

// ================= fused setup =================
// blockIdx.y: 0..5 weight cast+transpose | 6 zero | 7 W2f+bbf | 8 prep | 9 misc
struct WSet {
  const float* s[6]; u16* d[6];
  int K[6]; int N[6]; int dstride[6]; int coff[6];
};

__global__ __launch_bounds__(256) void k_setup(WSet ws,
                                               u32* __restrict__ zero_area,
                                               const float* __restrict__ proj_b,
                                               const float* __restrict__ pe_b2,
                                               const float* __restrict__ uw1,
                                               const float* __restrict__ ub1,
                                               const float* __restrict__ uw2,
                                               const float* __restrict__ ub2,
                                               u16* __restrict__ W2f,
                                               float* __restrict__ bbf,
                                               const int* __restrict__ coords,
                                               const float* __restrict__ feats,
                                               const float* __restrict__ pw1,
                                               const float* __restrict__ pb1,
                                               u16* __restrict__ A1,
                                               u16* __restrict__ A2,
                                               const float* __restrict__ wq,
                                               const float* __restrict__ wk,
                                               const float* __restrict__ wv,
                                               const float* __restrict__ proj_w_f,
                                               const float* __restrict__ pe_w2_f,
                                               u16* __restrict__ W1K,
                                               float* __restrict__ bcomb,
                                               const float* __restrict__ wo_f,
                                               const float* __restrict__ fw1_f,
                                               const float* __restrict__ bo_f,
                                               const float* __restrict__ fb1_f,
                                               u16* __restrict__ woK,
                                               float* __restrict__ bcomb2) {
  int w = blockIdx.y;
  if (w == 6) {  // zero: cnt, cursor, pS, pQ
    int idx = blockIdx.x * 256 + threadIdx.x;
    if (idx < 33088) zero_area[idx] = 0u;
    return;
  }
  if (w == 7) {  // fused tail weight W2f + bbf
    int n = blockIdx.x;
    if (n >= 64) return;
    int k = threadIdx.x;  // 0..255
    float s = 0.f;
    for (int j = 0; j < 64; j++) s += uw1[k * 64 + j] * uw2[(64 + j) * 64 + n];
    W2f[n * 320 + k] = f2bf(s);
    if (k < 64) W2f[n * 320 + 256 + k] = f2bf(uw2[k * 64 + n]);
    if (k == 0) {
      float b = ub2[n];
      for (int j = 0; j < 64; j++) b += ub1[j] * uw2[(64 + j) * 64 + n];
      bbf[n] = b;
    }
    return;
  }
  if (w == 8) {  // prep: A1 = [feats | relu(PE hidden)] (Nx192); A2[:,256:320] = feats bf16
    int r0 = blockIdx.x * 32;
#pragma unroll
    for (int s = 0; s < 3; s++) {
      int j = threadIdx.x + s * 256;  // 0..767 = 32 rows x 24 segs
      int row = j / 24, seg = j % 24;
      int n = r0 + row;
      u16 o[8];
      if (seg < 8) {
        const float* fp = feats + (size_t)n * 64 + seg * 8;
        float4 a = *(const float4*)fp;
        float4 b = *(const float4*)(fp + 4);
        o[0] = f2bf(a.x); o[1] = f2bf(a.y); o[2] = f2bf(a.z); o[3] = f2bf(a.w);
        o[4] = f2bf(b.x); o[5] = f2bf(b.y); o[6] = f2bf(b.z); o[7] = f2bf(b.w);
        *(uint4*)(A2 + (size_t)n * 320 + 256 + seg * 8) = *(uint4*)o;
      } else {
        int jj0 = (seg - 8) * 8;
        float x0 = (float)coords[n * 3 + 0] * (1.f / 127.f);
        float x1 = (float)coords[n * 3 + 1] * (1.f / 127.f);
        float x2 = (float)coords[n * 3 + 2] * (1.f / 127.f);
#pragma unroll
        for (int u = 0; u < 8; u++) {
          int jj = jj0 + u;
          float hv = pb1[jj] + x0 * pw1[jj] + x1 * pw1[128 + jj] + x2 * pw1[256 + jj];
          o[u] = f2bf(fmaxf(hv, 0.f));
        }
      }
      *(uint4*)(A1 + (size_t)n * 192 + seg * 8) = *(uint4*)o;
    }
    return;
  }
  if (w == 9) {  // bcomb | W1K cast | woK cast | bcomb2
    int bx = blockIdx.x;
    if (bx < 3) {
      const float* wsel = (bx == 0) ? wq : (bx == 1) ? wk : wv;
      int c = threadIdx.x;
      float s = 0.f;
      for (int d = 0; d < 256; d++) s += (proj_b[d] + pe_b2[d]) * wsel[d * 256 + c];
      bcomb[bx * 256 + c] = s;
    } else if (bx < 27) {
      int i0 = (bx - 3) * 2048 + threadIdx.x * 8;  // chunks never straddle 16384
      const float* src = (i0 < 16384) ? (proj_w_f + i0) : (pe_w2_f + (i0 - 16384));
      float4 a = *(const float4*)src;
      float4 b = *(const float4*)(src + 4);
      u16 o[8];
      o[0] = f2bf(a.x); o[1] = f2bf(a.y); o[2] = f2bf(a.z); o[3] = f2bf(a.w);
      o[4] = f2bf(b.x); o[5] = f2bf(b.y); o[6] = f2bf(b.z); o[7] = f2bf(b.w);
      *(uint4*)(W1K + i0) = *(uint4*)o;
    } else if (bx < 59) {
      int i0 = (bx - 27) * 2048 + threadIdx.x * 8;  // wo: 65536 floats
      float4 a = *(const float4*)(wo_f + i0);
      float4 b = *(const float4*)(wo_f + i0 + 4);
      u16 o[8];
      o[0] = f2bf(a.x); o[1] = f2bf(a.y); o[2] = f2bf(a.z); o[3] = f2bf(a.w);
      o[4] = f2bf(b.x); o[5] = f2bf(b.y); o[6] = f2bf(b.z); o[7] = f2bf(b.w);
      *(uint4*)(woK + i0) = *(uint4*)o;
    } else if (bx < 61) {
      int n2 = (bx - 59) * 256 + threadIdx.x;  // 0..511
      float s = fb1_f[n2];
      for (int d = 0; d < 256; d++) s += bo_f[d] * fw1_f[d * 512 + n2];
      bcomb2[n2] = s;
    }
    return;
  }
  // weight cast+transpose: S (K x N fp32) -> D[n*dstride+coff+k] bf16
  const float* S = ws.s[w]; u16* D = ws.d[w];
  int K = ws.K[w], N = ws.N[w], ds = ws.dstride[w], co = ws.coff[w];
  int ntx = N >> 5, tiles = ntx * (K >> 5);
  int t = blockIdx.x;
  if (t >= tiles) return;
  int n0 = (t % ntx) * 32, k0 = (t / ntx) * 32;
  __shared__ float st[32][33];
  int tr = threadIdx.x >> 3, tc4 = (threadIdx.x & 7) * 4;
  float4 v = *(const float4*)(S + (size_t)(k0 + tr) * N + n0 + tc4);
  st[tc4 + 0][tr] = v.x; st[tc4 + 1][tr] = v.y;
  st[tc4 + 2][tr] = v.z; st[tc4 + 3][tr] = v.w;
  __syncthreads();
  u16 o4[4];
  o4[0] = f2bf(st[tr][tc4 + 0]); o4[1] = f2bf(st[tr][tc4 + 1]);
  o4[2] = f2bf(st[tr][tc4 + 2]); o4[3] = f2bf(st[tr][tc4 + 3]);
  *(uint2*)(D + (size_t)(n0 + tr) * ds + co + k0 + tc4) = *(uint2*)o4;
}

// ================= combo: Wcomb GEMM | Wcomb2 GEMM | hist, one launch =================
// grid (4, 36): y<12 Wcomb (x<3), y in [12,20) Wcomb2, y in [20,36) hist
__global__ __launch_bounds__(256) void k_combo(const u16* __restrict__ qkvT,
                                               const u16* __restrict__ W1K,
                                               u16* __restrict__ Wcomb,
                                               const u16* __restrict__ fw1T,
                                               const u16* __restrict__ woK,
                                               u16* __restrict__ Wcomb2,
                                               const int* __restrict__ coords,
                                               u32* __restrict__ cnt) {
  int y = blockIdx.y;
  if (y >= 20) {  // hist
    int n = ((y - 20) * 4 + blockIdx.x) * 256 + threadIdx.x;
    int c = coords[n * 3] * 128 + coords[n * 3 + 1];
    atomicAdd(&cnt[c], 1u);
    return;
  }
  const u16 *A, *WT; u16* C; int K, N, bm, bn;
  if (y < 12) {
    if (blockIdx.x >= 3) return;
    A = qkvT; WT = W1K; C = Wcomb; K = 256; N = 192;
    bm = y * 64; bn = blockIdx.x * 64;
  } else {
    A = fw1T; WT = woK; C = Wcomb2; K = 256; N = 256;
    bm = (y - 12) * 64; bn = blockIdx.x * 64;
  }
  __shared__ __align__(16) char smem[16384];
  u16* AsB = (u16*)smem;            // [2][64*32]
  u16* BsB = AsB + 2 * 64 * 32;     // [2][64*32]
  u16* tile = (u16*)smem;           // [64][72] epilogue reuse
  const int tid = threadIdx.x;
  const int wave = tid >> 6, lane = tid & 63;
  const int wr = (wave >> 1) * 32, wc = (wave & 1) * 32;
  const int fr = lane & 15, fk = (lane >> 4) * 8, rq = (lane >> 4) * 4;
  const int grow = tid >> 2, gko = (tid & 3) * 8;

  f32x4 acc[2][2];
#pragma unroll
  for (int i = 0; i < 2; i++)
#pragma unroll
    for (int j = 0; j < 2; j++)
#pragma unroll
      for (int r = 0; r < 4; r++) acc[i][j][r] = 0.f;

  for (int k0 = 0; k0 < K; k0 += 64) {
#pragma unroll
    for (int h = 0; h < 2; h++) {
      gll16(A + (size_t)(bm + grow) * K + k0 + h * 32 + gko, AsB + h * 2048 + tid * 8);
      gll16(WT + (size_t)(bn + grow) * K + k0 + h * 32 + gko, BsB + h * 2048 + tid * 8);
    }
    __syncthreads();
#pragma unroll
    for (int h = 0; h < 2; h++) {
      short8 af[2], bg[2];
#pragma unroll
      for (int i = 0; i < 2; i++)
        af[i] = *(const short8*)&AsB[h * 2048 + (wr + i * 16 + fr) * 32 + fk];
#pragma unroll
      for (int j = 0; j < 2; j++)
        bg[j] = *(const short8*)&BsB[h * 2048 + (wc + j * 16 + fr) * 32 + fk];
#pragma unroll
      for (int i = 0; i < 2; i++)
#pragma unroll
        for (int j = 0; j < 2; j++)
          acc[i][j] = __builtin_amdgcn_mfma_f32_16x16x32_bf16(af[i], bg[j], acc[i][j], 0, 0, 0);
    }
    __syncthreads();
  }
#pragma unroll
  for (int j = 0; j < 2; j++) {
    int ccl = wc + j * 16 + fr;
#pragma unroll
    for (int i = 0; i < 2; i++) {
      int rl = wr + i * 16 + rq;
#pragma unroll
      for (int r = 0; r < 4; r++) tile[(rl + r) * 72 + ccl] = f2bf(acc[i][j][r]);
    }
  }
  __syncthreads();
#pragma unroll
  for (int t = 0; t < 2; t++) {
    int idx = t * 256 + tid;
    int row = idx >> 3, c8 = (idx & 7) * 8;
    *(uint4*)(C + (size_t)(bm + row) * N + bn + c8) = *(const uint4*)&tile[row * 72 + c8];
  }
}

// ================= scatter with fused full-prefix scan (redundant per block) =================
__global__ __launch_bounds__(256) void k_scatter(const int* __restrict__ coords,
                                                 const u32* __restrict__ cnt,
                                                 u32* __restrict__ startb,
                                                 u32* __restrict__ cursor,
                                                 u32* __restrict__ pts) {
  __shared__ u32 sb[16384];   // 64 KB: full exclusive prefix
  __shared__ u32 wsum[4];
  int t = threadIdx.x;
  int lane = t & 63, wid = t >> 6;
  int base = t * 64;
  u32 s = 0;
  for (int i = 0; i < 64; i++) s += cnt[base + i];
  u32 v = s;
#pragma unroll
  for (int off = 1; off < 64; off <<= 1) {
    u32 u = __shfl_up(v, off);
    if (lane >= off) v += u;
  }
  if (lane == 63) wsum[wid] = v;
  __syncthreads();
  u32 woff = 0;
  for (int w2 = 0; w2 < wid; w2++) woff += wsum[w2];
  u32 run = woff + v - s;  // exclusive prefix at cell base
  for (int i = 0; i < 64; i++) { sb[base + i] = run; run += cnt[base + i]; }
  __syncthreads();
  // strip-write this block's 256 cells to global startb (for later select)
  startb[blockIdx.x * 256 + t] = sb[blockIdx.x * 256 + t];
  // scatter this block's points using LDS prefix
  int n = blockIdx.x * 256 + t;
  int x = coords[n * 3], y = coords[n * 3 + 1], z = coords[n * 3 + 2];
  int c = x * 128 + y;
  u32 slot = atomicAdd(&cursor[c], 1u);
  pts[sb[c] + slot] = ((u32)z << 14) | (u32)n;  // z:7b | idx:14b
}

// ================= bf16 MFMA GEMM (h-pair loop) + optional fused select =================
// C = A(MxK,lda) @ WT(NxK)^T -> Cout(ldc). SEL: blocks with y >= M/BM run neighbor-select.
template <int BM, int BN, int ACT, bool SEL>
__global__ __launch_bounds__(256) void k_mgemm(
    const u16* __restrict__ A, const u16* __restrict__ WT,
    const float* __restrict__ bias,
    u16* __restrict__ Cout,
    int M, int K, int N, int lda, int ldc,
    const int* __restrict__ coords,
    const u32* __restrict__ startb,
    const u32* __restrict__ cnt,
    const u32* __restrict__ pts,
    int* __restrict__ idxo) {
  if (SEL && (int)blockIdx.y >= M / BM) {
    // ---- neighbor select, cell-sorted order ----
    int sb = ((int)blockIdx.y - M / BM) * gridDim.x + blockIdx.x;
    if (sb >= 64) return;
    int gid = sb * 256 + threadIdx.x;
    u32 pk = pts[gid];
    int n = (int)(pk & 16383u);
    int z = (int)(pk >> 14);
    int x = coords[n * 3], y = coords[n * 3 + 1];
    u32 best[16];
#pragma unroll
    for (int j = 0; j < 16; j++) best[j] = 0xFFFFFFFFu;
    const int dxs[13] = {0, -1, 1, 0, 0, -2, 2, 0, 0, -1, -1, 1, 1};
    const int dys[13] = {0, 0, 0, -1, 1, 0, 0, -2, 2, -1, 1, -1, 1};
    const int dbs[13] = {0, 1, 1, 1, 1, 2, 2, 2, 2, 2, 2, 2, 2};
#pragma unroll
    for (int t = 0; t < 13; t++) {
      int xx = x + dxs[t], yy = y + dys[t];
      if (xx < 0 || xx > 127 || yy < 0 || yy > 127) continue;
      int c = xx * 128 + yy;
      u32 s0 = startb[c], e0 = s0 + cnt[c];
      for (u32 i = s0; i < e0; ++i) {
        u32 p = pts[i];
        int zq = (int)(p >> 14);
        int id = (int)(p & 16383u);
        int az = z - zq; az = az < 0 ? -az : az;
        int dd = dbs[t] + az;
        u32 key = (dd <= 2) ? (((u32)dd << 14) | (u32)id) : 0xFFFFFFFFu;
#pragma unroll
        for (int j = 0; j < 16; j++) {
          u32 lo = min(best[j], key);
          u32 hi = max(best[j], key);
          best[j] = lo; key = hi;
        }
      }
    }
#pragma unroll
    for (int j = 0; j < 16; j++)
      idxo[gid * 16 + j] = (best[j] == 0xFFFFFFFFu) ? -1 : (int)(best[j] & 16383u);
    return;
  }

  constexpr int FM = BM / 32, FN = BN / 32;
  constexpr int RA = BM / 64, RB = BN / 64;
  constexpr int BNP = BN + 8;
  constexpr int STAGE = (BM + BN) * 128;
  constexpr int TILEB = BM * BNP * 2;
  constexpr int SMEMB = STAGE > TILEB ? STAGE : TILEB;
  __shared__ __align__(16) char smem[SMEMB];
  u16* AsB = (u16*)smem;
  u16* BsB = AsB + 2 * BM * 32;
  u16* tile = (u16*)smem;
  const int tid = threadIdx.x;
  const int wave = tid >> 6, lane = tid & 63;
  const int bm = blockIdx.y * BM, bn = blockIdx.x * BN;
  const int wr = (wave >> 1) * (BM / 2), wc = (wave & 1) * (BN / 2);
  const int fr = lane & 15, fk = (lane >> 4) * 8, rq = (lane >> 4) * 4;

  f32x4 acc[FM][FN];
#pragma unroll
  for (int i = 0; i < FM; i++)
#pragma unroll
    for (int j = 0; j < FN; j++)
#pragma unroll
      for (int r = 0; r < 4; r++) acc[i][j][r] = 0.f;

  for (int k0 = 0; k0 < K; k0 += 64) {
#pragma unroll
    for (int h = 0; h < 2; h++) {
#pragma unroll
      for (int r = 0; r < RA; r++) {
        int g2 = r * 256 + tid;
        gll16(A + (size_t)(bm + (g2 >> 2)) * lda + k0 + h * 32 + (g2 & 3) * 8,
              AsB + h * BM * 32 + g2 * 8);
      }
#pragma unroll
      for (int r = 0; r < RB; r++) {
        int g2 = r * 256 + tid;
        gll16(WT + (size_t)(bn + (g2 >> 2)) * K + k0 + h * 32 + (g2 & 3) * 8,
              BsB + h * BN * 32 + g2 * 8);
      }
    }
    __syncthreads();
#pragma unroll
    for (int h = 0; h < 2; h++) {
      short8 af[FM], bg[FN];
#pragma unroll
      for (int i = 0; i < FM; i++)
        af[i] = *(const short8*)&AsB[h * BM * 32 + (wr + i * 16 + fr) * 32 + fk];
#pragma unroll
      for (int j = 0; j < FN; j++)
        bg[j] = *(const short8*)&BsB[h * BN * 32 + (wc + j * 16 + fr) * 32 + fk];
#pragma unroll
      for (int i = 0; i < FM; i++)
#pragma unroll
        for (int j = 0; j < FN; j++)
          acc[i][j] = __builtin_amdgcn_mfma_f32_16x16x32_bf16(af[i], bg[j], acc[i][j], 0, 0, 0);
    }
    __syncthreads();
  }

#pragma unroll
  for (int j = 0; j < FN; j++) {
    int ccl = wc + j * 16 + fr;
    float bval = bias ? bias[bn + ccl] : 0.f;
#pragma unroll
    for (int i = 0; i < FM; i++) {
      int rl = wr + i * 16 + rq;
#pragma unroll
      for (int r = 0; r < 4; r++) {
        float v = acc[i][j][r] + bval;
        if (ACT) v = fmaxf(v, 0.f);
        tile[(rl + r) * BNP + ccl] = f2bf(v);
      }
    }
  }
  __syncthreads();
  constexpr int RPW = BN / 8;
  constexpr int PT = BM * BN / 8 / 256;
#pragma unroll
  for (int t = 0; t < PT; t++) {
    int idx = t * 256 + tid;
    int row = idx / RPW, c8 = (idx % RPW) * 8;
    *(uint4*)(Cout + (size_t)(bm + row) * ldc + bn + c8) =
        *(const uint4*)&tile[row * BNP + c8];
  }
}

// ================= attention -> AO (stride 256), cell-sorted =================
__global__ __launch_bounds__(256) void k_attn(const u16* __restrict__ QKV,
                                              const u32* __restrict__ pts,
                                              const int* __restrict__ idx,
                                              const float* __restrict__ bq,
                                              const float* __restrict__ bk,
                                              const float* __restrict__ bv,
                                              u16* __restrict__ outp) {
  int gid = blockIdx.x * 256 + threadIdx.x;
  int s4 = gid >> 3;  // sorted position
  int n = (int)(pts[s4] & 16383u), h = gid & 7;
  const int* ip = idx + s4 * 16;
  const int hb = h * 32;
  float q[32];
  {
    int i0 = ip[0];
    const u16* qp = QKV + (size_t)i0 * 768 + hb;
#pragma unroll
    for (int j = 0; j < 32; j += 8) ldbf8(qp + j, &q[j]);
#pragma unroll
    for (int j = 0; j < 32; j++) q[j] += bq[hb + j];
  }
  float qbk = 0.f;
#pragma unroll
  for (int j = 0; j < 32; j++) qbk += q[j] * bk[hb + j];
  float s[16]; int ii[16];
#pragma unroll
  for (int m = 0; m < 16; m++) {
    int i = ip[m]; ii[m] = i;
    float d = qbk;
    if (i >= 0) {
      const u16* kp = QKV + (size_t)i * 768 + 256 + hb;
      float kv[32];
#pragma unroll
      for (int j = 0; j < 32; j += 8) ldbf8(kp + j, &kv[j]);
#pragma unroll
      for (int j = 0; j < 32; j++) d += q[j] * kv[j];
    }
    s[m] = d * 0.17677669529663689f;  // 1/sqrt(32)
  }
  float mx = s[0];
#pragma unroll
  for (int m = 1; m < 16; m++) mx = fmaxf(mx, s[m]);
  float sum = 0.f;
#pragma unroll
  for (int m = 0; m < 16; m++) { s[m] = __expf(s[m] - mx); sum += s[m]; }
  float inv = 1.f / sum;
  float o[32];
#pragma unroll
  for (int j = 0; j < 32; j++) o[j] = 0.f;
#pragma unroll
  for (int m = 0; m < 16; m++) {
    if (ii[m] >= 0) {
      const u16* vp = QKV + (size_t)ii[m] * 768 + 512 + hb;
      float vv[32];
#pragma unroll
      for (int j = 0; j < 32; j += 8) ldbf8(vp + j, &vv[j]);
#pragma unroll
      for (int j = 0; j < 32; j++) o[j] += s[m] * vv[j];
    }
  }
  u16* op = outp + (size_t)n * 256 + hb;
#pragma unroll
  for (int j = 0; j < 32; j += 8) {
    u16 tmp[8];
#pragma unroll
    for (int jj = 0; jj < 8; jj++) tmp[jj] = f2bf(o[j + jj] * inv + bv[hb + j + jj]);
    *(uint4*)(op + j) = *(uint4*)tmp;
  }
}

// ================= mega-fused tail: h1 + ffn2 + LN + f GEMM + BN stats =================
// Block owns 64 rows. x accumulated as K-slices:
//   x = AO@wo^T  +  h1a@fw2[.,0:256]^T  +  h1b@fw2[.,256:512]^T,  h1 halves computed
// in-block (relu(AO@Wcomb2^T+bcomb2)), bf16-rounded to LDS exactly as the old h1B path.
__global__ __launch_bounds__(256) void k_ffn2f(const u16* __restrict__ AO,
                                               const u16* __restrict__ WTBIG,
                                               const u16* __restrict__ Wcomb2,
                                               const float* __restrict__ bcomb2,
                                               const float* __restrict__ bo,
                                               const float* __restrict__ fb2,
                                               const float* __restrict__ g,
                                               const float* __restrict__ b,
                                               const u16* __restrict__ A2,
                                               const u16* __restrict__ W2f,
                                               const float* __restrict__ bbf,
                                               float* __restrict__ fB,
                                               float* __restrict__ pS,
                                               float* __restrict__ pQ) {
  constexpr int BM = 64, FM = 2, FN = 8;
  constexpr int ADP2 = 328;   // aT stride (u16): 256 y + 64 feats + 8 pad
  constexpr int HDP = 264;    // h1T stride (u16): 256 + 8 pad
  // region 1 (41984 B): staging As[2][64*32]+Bs[2][256*32]  OR  aT[64][328]
  // region 2 (33792 B): h1T[64][264]  OR  Bs2[2][2048] (f-GEMM W2f staging)
  __shared__ __align__(16) char smem1[41984];
  __shared__ __align__(16) char smem2[33792];
  __shared__ float lnS[64][2], lnQ[64][2];
  __shared__ float colS[64][2], colQ[64][2];
  u16* AsB = (u16*)smem1;                // [2][2048]
  u16* BsB = AsB + 2 * 64 * 32;          // [2][8192]
  u16* aT  = (u16*)smem1;                // [64][328]
  u16* h1T = (u16*)smem2;                // [64][264]
  u16* Bs2 = (u16*)smem2;                // [2][2048]
  const int tid = threadIdx.x;
  const int wave = tid >> 6, lane = tid & 63;
  const int bm = blockIdx.x * BM;
  const int wr = (wave >> 1) * 32, wc = (wave & 1) * 128;
  const int fr = lane & 15, fk = (lane >> 4) * 8, rq = (lane >> 4) * 4;

  f32x4 xacc[FM][FN];
#pragma unroll
  for (int i = 0; i < FM; i++)
#pragma unroll
    for (int j = 0; j < FN; j++)
#pragma unroll
      for (int r = 0; r < 4; r++) xacc[i][j][r] = 0.f;

  // ---- P0: x += AO @ WTBIG[:,0:256]^T  (K slice 0:256) ----
  for (int k0 = 0; k0 < 256; k0 += 64) {
#pragma unroll
    for (int h = 0; h < 2; h++) {
      gll16(AO + (size_t)(bm + (tid >> 2)) * 256 + k0 + h * 32 + (tid & 3) * 8,
            AsB + h * 2048 + tid * 8);
#pragma unroll
      for (int r = 0; r < 4; r++) {
        int g2 = r * 256 + tid;
        gll16(WTBIG + (size_t)(g2 >> 2) * 768 + k0 + h * 32 + (g2 & 3) * 8,
              BsB + h * 8192 + g2 * 8);
      }
    }
    __syncthreads();
#pragma unroll
    for (int h = 0; h < 2; h++) {
      short8 af[FM], bg[FN];
#pragma unroll
      for (int i = 0; i < FM; i++)
        af[i] = *(const short8*)&AsB[h * 2048 + (wr + i * 16 + fr) * 32 + fk];
#pragma unroll
      for (int j = 0; j < FN; j++)
        bg[j] = *(const short8*)&BsB[h * 8192 + (wc + j * 16 + fr) * 32 + fk];
#pragma unroll
      for (int i = 0; i < FM; i++)
#pragma unroll
        for (int j = 0; j < FN; j++)
          xacc[i][j] = __builtin_amdgcn_mfma_f32_16x16x32_bf16(af[i], bg[j], xacc[i][j], 0, 0, 0);
    }
    __syncthreads();
  }

  // ---- two h1 halves: compute h1 -> h1T, then x += h1half @ WTBIG slice ----
#pragma unroll
  for (int half = 0; half < 2; half++) {
    // P(half)a: h1half = relu(AO @ Wcomb2[half*256:+256]^T + bcomb2[half*256:+256])
    f32x4 hacc[FM][FN];
#pragma unroll
    for (int i = 0; i < FM; i++)
#pragma unroll
      for (int j = 0; j < FN; j++)
#pragma unroll
        for (int r = 0; r < 4; r++) hacc[i][j][r] = 0.f;
    const u16* Wc2 = Wcomb2 + (size_t)half * 256 * 256;
    for (int k0 = 0; k0 < 256; k0 += 64) {
#pragma unroll
      for (int h = 0; h < 2; h++) {
        gll16(AO + (size_t)(bm + (tid >> 2)) * 256 + k0 + h * 32 + (tid & 3) * 8,
              AsB + h * 2048 + tid * 8);
#pragma unroll
        for (int r = 0; r < 4; r++) {
          int g2 = r * 256 + tid;
          gll16(Wc2 + (size_t)(g2 >> 2) * 256 + k0 + h * 32 + (g2 & 3) * 8,
                BsB + h * 8192 + g2 * 8);
        }
      }
      __syncthreads();
#pragma unroll
      for (int h = 0; h < 2; h++) {
        short8 af[FM], bg[FN];
#pragma unroll
        for (int i = 0; i < FM; i++)
          af[i] = *(const short8*)&AsB[h * 2048 + (wr + i * 16 + fr) * 32 + fk];
#pragma unroll
        for (int j = 0; j < FN; j++)
          bg[j] = *(const short8*)&BsB[h * 8192 + (wc + j * 16 + fr) * 32 + fk];
#pragma unroll
        for (int i = 0; i < FM; i++)
#pragma unroll
          for (int j = 0; j < FN; j++)
            hacc[i][j] = __builtin_amdgcn_mfma_f32_16x16x32_bf16(af[i], bg[j], hacc[i][j], 0, 0, 0);
      }
      __syncthreads();
    }
    // write relu(hacc + bias) bf16 into h1T (identical rounding to old h1B path)
#pragma unroll
    for (int j = 0; j < FN; j++) {
      int cc = wc + j * 16 + fr;
      float bval = bcomb2[half * 256 + cc];
#pragma unroll
      for (int i = 0; i < FM; i++) {
        int rl = wr + i * 16 + rq;
#pragma unroll
        for (int r = 0; r < 4; r++)
          h1T[(rl + r) * HDP + cc] = f2bf(fmaxf(hacc[i][j][r] + bval, 0.f));
      }
    }
    __syncthreads();
    // P(half)b: x += h1half @ WTBIG[:, 256+half*256 : +256]^T
    const int kbase = 256 + half * 256;
    for (int k0 = 0; k0 < 256; k0 += 64) {
#pragma unroll
      for (int h = 0; h < 2; h++) {
#pragma unroll
        for (int r = 0; r < 4; r++) {
          int g2 = r * 256 + tid;
          gll16(WTBIG + (size_t)(g2 >> 2) * 768 + kbase + k0 + h * 32 + (g2 & 3) * 8,
                BsB + h * 8192 + g2 * 8);
        }
      }
      __syncthreads();
#pragma unroll
      for (int h = 0; h < 2; h++) {
        short8 af[FM], bg[FN];
#pragma unroll
        for (int i = 0; i < FM; i++)
          af[i] = *(const short8*)&h1T[(wr + i * 16 + fr) * HDP + k0 + h * 32 + fk];
#pragma unroll
        for (int j = 0; j < FN; j++)
          bg[j] = *(const short8*)&BsB[h * 8192 + (wc + j * 16 + fr) * 32 + fk];
#pragma unroll
        for (int i = 0; i < FM; i++)
#pragma unroll
          for (int j = 0; j < FN; j++)
            xacc[i][j] = __builtin_amdgcn_mfma_f32_16x16x32_bf16(af[i], bg[j], xacc[i][j], 0, 0, 0);
      }
      __syncthreads();
    }
  }

  // ---- P3: bias, LN stats, normalize -> y into aT; feats into aT ----
#pragma unroll
  for (int j = 0; j < FN; j++) {
    int cc = wc + j * 16 + fr;
    float bval = bo[cc] + fb2[cc];
#pragma unroll
    for (int i = 0; i < FM; i++)
#pragma unroll
      for (int r = 0; r < 4; r++) xacc[i][j][r] += bval;
  }
#pragma unroll
  for (int i = 0; i < FM; i++) {
#pragma unroll
    for (int r = 0; r < 4; r++) {
      float sm = 0.f, sq = 0.f;
#pragma unroll
      for (int j = 0; j < FN; j++) { float t = xacc[i][j][r]; sm += t; sq += t * t; }
#pragma unroll
      for (int off = 1; off < 16; off <<= 1) {
        sm += __shfl_xor(sm, off);
        sq += __shfl_xor(sq, off);
      }
      if (fr == 0) {
        int row = wr + i * 16 + rq + r;
        lnS[row][wave & 1] = sm;
        lnQ[row][wave & 1] = sq;
      }
    }
  }
  __syncthreads();   // lnS/lnQ ready; staging fully consumed -> aT may overwrite
#pragma unroll
  for (int i = 0; i < FM; i++) {
#pragma unroll
    for (int r = 0; r < 4; r++) {
      int row = wr + i * 16 + rq + r;
      float sm = lnS[row][0] + lnS[row][1];
      float sq = lnQ[row][0] + lnQ[row][1];
      float mu = sm * (1.f / 256.f);
      float var = sq * (1.f / 256.f) - mu * mu;
      float rstd = rsqrtf(var + kEPS);
#pragma unroll
      for (int j = 0; j < FN; j++) {
        int cc = wc + j * 16 + fr;
        float val = (xacc[i][j][r] - mu) * rstd * g[cc] + b[cc];
        aT[row * ADP2 + cc] = f2bf(val);
      }
    }
  }
  // feats: A2[:,256:320] -> aT[:,256:320]
#pragma unroll
  for (int t = 0; t < 2; t++) {
    int idx = t * 256 + tid;
    int row = idx >> 3, c8 = (idx & 7) * 8;
    *(uint4*)&aT[row * ADP2 + 256 + c8] =
        *(const uint4*)(A2 + (size_t)(bm + row) * 320 + 256 + c8);
  }
  __syncthreads();

  // ---- P4: f GEMM K=320, A from aT (LDS), B = W2f staged into Bs2 (region 2) ----
  const int wr3 = (wave >> 1) * 32, wc3 = (wave & 1) * 32;
  const int grow = tid >> 2, gko = (tid & 3) * 8;
  f32x4 acc2[2][2];
#pragma unroll
  for (int i = 0; i < 2; i++)
#pragma unroll
    for (int j = 0; j < 2; j++)
#pragma unroll
      for (int r = 0; r < 4; r++) acc2[i][j][r] = 0.f;
  for (int k0 = 0; k0 < 320; k0 += 64) {
#pragma unroll
    for (int h = 0; h < 2; h++)
      gll16(W2f + (size_t)grow * 320 + k0 + h * 32 + gko, Bs2 + h * 2048 + tid * 8);
    __syncthreads();
#pragma unroll
    for (int h = 0; h < 2; h++) {
      short8 af[2], bg[2];
#pragma unroll
      for (int i = 0; i < 2; i++)
        af[i] = *(const short8*)&aT[(wr3 + i * 16 + fr) * ADP2 + k0 + h * 32 + fk];
#pragma unroll
      for (int j = 0; j < 2; j++)
        bg[j] = *(const short8*)&Bs2[h * 2048 + (wc3 + j * 16 + fr) * 32 + fk];
#pragma unroll
      for (int i = 0; i < 2; i++)
#pragma unroll
        for (int j = 0; j < 2; j++)
          acc2[i][j] = __builtin_amdgcn_mfma_f32_16x16x32_bf16(af[i], bg[j], acc2[i][j], 0, 0, 0);
    }
    __syncthreads();
  }
  // bias + fB write + column stats
  float cS[2] = {0.f, 0.f}, cQ[2] = {0.f, 0.f};
#pragma unroll
  for (int j = 0; j < 2; j++) {
    int col = wc3 + j * 16 + fr;
    float bv = bbf[col];
#pragma unroll
    for (int i = 0; i < 2; i++) {
      int rbase = bm + wr3 + i * 16 + rq;
#pragma unroll
      for (int r = 0; r < 4; r++) {
        float v = acc2[i][j][r] + bv;
        fB[(size_t)(rbase + r) * 64 + col] = v;
        cS[j] += v; cQ[j] += v * v;
      }
    }
  }
#pragma unroll
  for (int off = 16; off < 64; off <<= 1) {
#pragma unroll
    for (int j = 0; j < 2; j++) {
      cS[j] += __shfl_xor(cS[j], off);
      cQ[j] += __shfl_xor(cQ[j], off);
    }
  }
  if ((lane >> 4) == 0) {
#pragma unroll
    for (int j = 0; j < 2; j++) {
      colS[wc3 + j * 16 + fr][wave >> 1] = cS[j];
      colQ[wc3 + j * 16 + fr][wave >> 1] = cQ[j];
    }
  }
  __syncthreads();
  if (tid < 64) {
    atomicAdd(&pS[tid], colS[tid][0] + colS[tid][1]);
    atomicAdd(&pQ[tid], colQ[tid][0] + colQ[tid][1]);
  }
}

// ================= BN finalize (per-block recompute) + apply + relu =================
__global__ __launch_bounds__(256) void k_bnapply(const float* __restrict__ f,
                                                 const float* __restrict__ pS,
                                                 const float* __restrict__ pQ,
                                                 const float* __restrict__ g,
                                                 const float* __restrict__ b,
                                                 float* __restrict__ out) {
  __shared__ float cf_s[64], sh_s[64];
  if (threadIdx.x < 64) {
    int c = threadIdx.x;
    float S = pS[c], Q = pQ[c];
    float m = S * (1.f / 16384.f);
    float var = Q * (1.f / 16384.f) - m * m;
    float cf = rsqrtf(var + kEPS) * g[c];
    cf_s[c] = cf;
    sh_s[c] = b[c] - m * cf;
  }
  __syncthreads();
  int gid = blockIdx.x * 256 + threadIdx.x;
  int e = gid * 4, col = e & 63;
  float4 v = *(const float4*)(f + e);
  float4 cf = *(const float4*)(cf_s + col);
  float4 sh = *(const float4*)(sh_s + col);
  float4 o;
  o.x = fmaxf(v.x * cf.x + sh.x, 0.f);
  o.y = fmaxf(v.y * cf.y + sh.y, 0.f);
  o.z = fmaxf(v.z * cf.z + sh.z, 0.f);
  o.w = fmaxf(v.w * cf.w + sh.w, 0.f);
  *(float4*)(out + e) = o;
}

// ================= launch =================
extern "C" void kernel_launch(void* const* d_in, const int* in_sizes, int n_in,
                              void* d_out, int out_size, void* d_ws, size_t ws_size,
                              hipStream_t stream) {
  (void)in_sizes; (void)n_in; (void)out_size; (void)ws_size;
  const int*   coords = (const int*)d_in[0];
  const float* feats  = (const float*)d_in[1];
  const float* pe_w1  = (const float*)d_in[2];
  const float* pe_b1  = (const float*)d_in[3];
  const float* pe_w2  = (const float*)d_in[4];
  const float* pe_b2  = (const float*)d_in[5];
  const float* proj_w = (const float*)d_in[6];
  const float* proj_b = (const float*)d_in[7];
  const float* wq  = (const float*)d_in[8];
  const float* bq  = (const float*)d_in[9];
  const float* wk  = (const float*)d_in[10];
  const float* bk  = (const float*)d_in[11];
  const float* wv  = (const float*)d_in[12];
  const float* bv  = (const float*)d_in[13];
  const float* wo  = (const float*)d_in[14];
  const float* bo  = (const float*)d_in[15];
  const float* fw1 = (const float*)d_in[16];
  const float* fb1 = (const float*)d_in[17];
  const float* fw2 = (const float*)d_in[18];
  const float* fb2 = (const float*)d_in[19];
  const float* lng = (const float*)d_in[20];
  const float* lnb = (const float*)d_in[21];
  const float* uw1 = (const float*)d_in[22];
  const float* ub1 = (const float*)d_in[23];
  const float* uw2 = (const float*)d_in[24];
  const float* ub2 = (const float*)d_in[25];
  const float* bng = (const float*)d_in[26];
  const float* bnb = (const float*)d_in[27];
  float* out = (float*)d_out;

  char* Wc = (char*)d_ws;
  const size_t MB = 1u << 20;
  u16*   A1    = (u16*)(Wc + 0 * MB);    // 6MB
  u16*   QKVb  = (u16*)(Wc + 14 * MB);   // 24MB (14..38)
  u16*   AO    = (u16*)(Wc + 38 * MB);   // 8MB attn out [16384][256]
  u16*   A2    = (u16*)(Wc + 78 * MB);   // 10MB [unused y | feats]
  float* fB    = (float*)(Wc + 0 * MB);  // 4MB over dead A1

  u16* qkvT   = (u16*)(Wc + 88 * MB);    // 768 x 256
  u16* WTBIG  = qkvT + 196608;           // 256 x 768 ([woT | fw2T] rows)
  u16* fw1T   = WTBIG + 196608;          // 512 x 256
  u16* woK    = fw1T + 131072;           // 256 x 256 (row-major cast of wo)
  u16* W1K    = woK + 65536;             // 192 x 256
  u16* W2f    = W1K + 49152;             // 64 x 320
  u16* Wcomb  = W2f + 20480;             // 768 x 192
  u16* Wcomb2 = Wcomb + 147456;          // 512 x 256 (WT layout of wo@fw1)
  float* bbf    = (float*)(Wcomb2 + 131072);  // 64
  float* bcomb  = bbf + 64;              // 768
  float* bcomb2 = bcomb + 768;           // 512

  u32* Z      = (u32*)(Wc + 90 * MB);
  u32* cnt    = Z;                        // 16384  (zeroed)
  u32* cursor = Z + 16384;                // 16384  (zeroed)
  float* pS   = (float*)(Z + 32768);      // 64     (zeroed)
  float* pQ   = (float*)(Z + 32832);      // 64     (zeroed)
  u32* startb = Z + 33280;                // 16384
  u32* pts    = Z + 49664;                // 16384
  int* idxb   = (int*)(Z + 66048);        // N*16 (by sorted position)

  WSet ws;
  ws.s[0] = wq;  ws.d[0] = qkvT;          ws.K[0] = 256; ws.N[0] = 256; ws.dstride[0] = 256; ws.coff[0] = 0;
  ws.s[1] = wk;  ws.d[1] = qkvT + 65536;  ws.K[1] = 256; ws.N[1] = 256; ws.dstride[1] = 256; ws.coff[1] = 0;
  ws.s[2] = wv;  ws.d[2] = qkvT + 131072; ws.K[2] = 256; ws.N[2] = 256; ws.dstride[2] = 256; ws.coff[2] = 0;
  ws.s[3] = wo;  ws.d[3] = WTBIG;         ws.K[3] = 256; ws.N[3] = 256; ws.dstride[3] = 768; ws.coff[3] = 0;
  ws.s[4] = fw1; ws.d[4] = fw1T;          ws.K[4] = 256; ws.N[4] = 512; ws.dstride[4] = 256; ws.coff[4] = 0;
  ws.s[5] = fw2; ws.d[5] = WTBIG;         ws.K[5] = 512; ws.N[5] = 256; ws.dstride[5] = 768; ws.coff[5] = 256;

  // 1. setup
  k_setup<<<dim3(512, 10), 256, 0, stream>>>(ws, Z, proj_b, pe_b2,
                                             uw1, ub1, uw2, ub2, W2f, bbf,
                                             coords, feats, pe_w1, pe_b1, A1, A2,
                                             wq, wk, wv, proj_w, pe_w2, W1K, bcomb,
                                             wo, fw1, bo, fb1, woK, bcomb2);
  // 2. combo: Wcomb GEMM + Wcomb2 GEMM + hist
  k_combo<<<dim3(4, 36), 256, 0, stream>>>(qkvT, W1K, Wcomb, fw1T, woK, Wcomb2,
                                           coords, cnt);
  // 3. scatter (+ fused redundant scan)
  k_scatter<<<64, 256, 0, stream>>>(coords, cnt, startb, cursor, pts);
  // 4. QKV (K=192, N=768) + fused neighbor-select (y >= 128)
  k_mgemm<128, 128, 0, true><<<dim3(6, 139), 256, 0, stream>>>(
      A1, Wcomb, bcomb, QKVb, kN, 192, 768, 192, 768,
      coords, startb, cnt, pts, idxb);
  // 5. attention -> AO (stride 256)
  k_attn<<<512, 256, 0, stream>>>(QKVb, pts, idxb, bq, bk, bv, AO);
  // 6. mega-fused tail: h1 + ffn2 + LN + f GEMM + BN stats
  k_ffn2f<<<256, 256, 0, stream>>>(AO, WTBIG, Wcomb2, bcomb2, bo, fb2, lng, lnb,
                                   A2, W2f, bbf, fB, pS, pQ);
  // 7. BN finalize (per-block) + apply
  k_bnapply<<<1024, 256, 0, stream>>>(fB, pS, pQ, bng, bnb, out);
}

// Round 12
// 225.752 us; speedup vs baseline: 1.0446x; 1.0446x over previous
//
#include <hip/hip_runtime.h>
#include <stdint.h>

typedef unsigned short u16;
typedef unsigned int   u32;
typedef __attribute__((ext_vector_type(8))) short short8;
typedef __attribute__((ext_vector_type(4))) float f32x4;

static constexpr int kN = 16384;
static constexpr float kEPS = 1e-5f;

__device__ __forceinline__ u16 f2bf(float x) {
  u32 u = __float_as_uint(x);
  u32 r = (u + 0x7fffu + ((u >> 16) & 1u)) >> 16;
  return (u16)r;
}
__device__ __forceinline__ float bf2f(u16 x) {
  return __uint_as_float(((u32)x) << 16);
}
__device__ __forceinline__ void ldbf8(const u16* p, float* o) {
  uint4 v = *(const uint4*)p;
  o[0] = __uint_as_float(v.x << 16);  o[1] = __uint_as_float(v.x & 0xffff0000u);
  o[2] = __uint_as_float(v.y << 16);  o[3] = __uint_as_float(v.y & 0xffff0000u);
  o[4] = __uint_as_float(v.z << 16);  o[5] = __uint_as_float(v.z & 0xffff0000u);
  o[6] = __uint_as_float(v.w << 16);  o[7] = __uint_as_float(v.w & 0xffff0000u);
}
__device__ __forceinline__ void gll16(const u16* g, u16* l) {
  __builtin_amdgcn_global_load_lds(
      (const __attribute__((address_space(1))) void*)g,
      (__attribute__((address_space(3))) void*)l, 16, 0, 0);
}

// ================= fused setup =================
// blockIdx.y: 0..5 weight cast+transpose | 6 zero | 7 W2f+bbf | 8 prep | 9 misc
struct WSet {
  const float* s[6]; u16* d[6];
  int K[6]; int N[6]; int dstride[6]; int coff[6];
};

__global__ __launch_bounds__(256) void k_setup(WSet ws,
                                               u32* __restrict__ zero_area,
                                               const float* __restrict__ proj_b,
                                               const float* __restrict__ pe_b2,
                                               const float* __restrict__ uw1,
                                               const float* __restrict__ ub1,
                                               const float* __restrict__ uw2,
                                               const float* __restrict__ ub2,
                                               u16* __restrict__ W2f,
                                               float* __restrict__ bbf,
                                               const int* __restrict__ coords,
                                               const float* __restrict__ feats,
                                               const float* __restrict__ pw1,
                                               const float* __restrict__ pb1,
                                               u16* __restrict__ A1,
                                               u16* __restrict__ A2,
                                               const float* __restrict__ wq,
                                               const float* __restrict__ wk,
                                               const float* __restrict__ wv,
                                               const float* __restrict__ proj_w_f,
                                               const float* __restrict__ pe_w2_f,
                                               u16* __restrict__ W1K,
                                               float* __restrict__ bcomb,
                                               const float* __restrict__ wo_f,
                                               const float* __restrict__ fw1_f,
                                               const float* __restrict__ bo_f,
                                               const float* __restrict__ fb1_f,
                                               u16* __restrict__ woK,
                                               float* __restrict__ bcomb2) {
  int w = blockIdx.y;
  if (w == 6) {  // zero: cnt, cursor, pS, pQ
    int idx = blockIdx.x * 256 + threadIdx.x;
    if (idx < 33088) zero_area[idx] = 0u;
    return;
  }
  if (w == 7) {  // fused tail weight W2f + bbf
    int n = blockIdx.x;
    if (n >= 64) return;
    int k = threadIdx.x;  // 0..255
    float s = 0.f;
    for (int j = 0; j < 64; j++) s += uw1[k * 64 + j] * uw2[(64 + j) * 64 + n];
    W2f[n * 320 + k] = f2bf(s);
    if (k < 64) W2f[n * 320 + 256 + k] = f2bf(uw2[k * 64 + n]);
    if (k == 0) {
      float b = ub2[n];
      for (int j = 0; j < 64; j++) b += ub1[j] * uw2[(64 + j) * 64 + n];
      bbf[n] = b;
    }
    return;
  }
  if (w == 8) {  // prep: A1 = [feats | relu(PE hidden)] (Nx192); A2[:,256:320] = feats bf16
    int r0 = blockIdx.x * 32;
#pragma unroll
    for (int s = 0; s < 3; s++) {
      int j = threadIdx.x + s * 256;  // 0..767 = 32 rows x 24 segs
      int row = j / 24, seg = j % 24;
      int n = r0 + row;
      u16 o[8];
      if (seg < 8) {
        const float* fp = feats + (size_t)n * 64 + seg * 8;
        float4 a = *(const float4*)fp;
        float4 b = *(const float4*)(fp + 4);
        o[0] = f2bf(a.x); o[1] = f2bf(a.y); o[2] = f2bf(a.z); o[3] = f2bf(a.w);
        o[4] = f2bf(b.x); o[5] = f2bf(b.y); o[6] = f2bf(b.z); o[7] = f2bf(b.w);
        *(uint4*)(A2 + (size_t)n * 320 + 256 + seg * 8) = *(uint4*)o;
      } else {
        int jj0 = (seg - 8) * 8;
        float x0 = (float)coords[n * 3 + 0] * (1.f / 127.f);
        float x1 = (float)coords[n * 3 + 1] * (1.f / 127.f);
        float x2 = (float)coords[n * 3 + 2] * (1.f / 127.f);
#pragma unroll
        for (int u = 0; u < 8; u++) {
          int jj = jj0 + u;
          float hv = pb1[jj] + x0 * pw1[jj] + x1 * pw1[128 + jj] + x2 * pw1[256 + jj];
          o[u] = f2bf(fmaxf(hv, 0.f));
        }
      }
      *(uint4*)(A1 + (size_t)n * 192 + seg * 8) = *(uint4*)o;
    }
    return;
  }
  if (w == 9) {  // bcomb | W1K cast | woK cast | bcomb2
    int bx = blockIdx.x;
    if (bx < 3) {
      const float* wsel = (bx == 0) ? wq : (bx == 1) ? wk : wv;
      int c = threadIdx.x;
      float s = 0.f;
      for (int d = 0; d < 256; d++) s += (proj_b[d] + pe_b2[d]) * wsel[d * 256 + c];
      bcomb[bx * 256 + c] = s;
    } else if (bx < 27) {
      int i0 = (bx - 3) * 2048 + threadIdx.x * 8;  // chunks never straddle 16384
      const float* src = (i0 < 16384) ? (proj_w_f + i0) : (pe_w2_f + (i0 - 16384));
      float4 a = *(const float4*)src;
      float4 b = *(const float4*)(src + 4);
      u16 o[8];
      o[0] = f2bf(a.x); o[1] = f2bf(a.y); o[2] = f2bf(a.z); o[3] = f2bf(a.w);
      o[4] = f2bf(b.x); o[5] = f2bf(b.y); o[6] = f2bf(b.z); o[7] = f2bf(b.w);
      *(uint4*)(W1K + i0) = *(uint4*)o;
    } else if (bx < 59) {
      int i0 = (bx - 27) * 2048 + threadIdx.x * 8;  // wo: 65536 floats
      float4 a = *(const float4*)(wo_f + i0);
      float4 b = *(const float4*)(wo_f + i0 + 4);
      u16 o[8];
      o[0] = f2bf(a.x); o[1] = f2bf(a.y); o[2] = f2bf(a.z); o[3] = f2bf(a.w);
      o[4] = f2bf(b.x); o[5] = f2bf(b.y); o[6] = f2bf(b.z); o[7] = f2bf(b.w);
      *(uint4*)(woK + i0) = *(uint4*)o;
    } else if (bx < 61) {
      int n2 = (bx - 59) * 256 + threadIdx.x;  // 0..511
      float s = fb1_f[n2];
      for (int d = 0; d < 256; d++) s += bo_f[d] * fw1_f[d * 512 + n2];
      bcomb2[n2] = s;
    }
    return;
  }
  // weight cast+transpose: S (K x N fp32) -> D[n*dstride+coff+k] bf16
  const float* S = ws.s[w]; u16* D = ws.d[w];
  int K = ws.K[w], N = ws.N[w], ds = ws.dstride[w], co = ws.coff[w];
  int ntx = N >> 5, tiles = ntx * (K >> 5);
  int t = blockIdx.x;
  if (t >= tiles) return;
  int n0 = (t % ntx) * 32, k0 = (t / ntx) * 32;
  __shared__ float st[32][33];
  int tr = threadIdx.x >> 3, tc4 = (threadIdx.x & 7) * 4;
  float4 v = *(const float4*)(S + (size_t)(k0 + tr) * N + n0 + tc4);
  st[tc4 + 0][tr] = v.x; st[tc4 + 1][tr] = v.y;
  st[tc4 + 2][tr] = v.z; st[tc4 + 3][tr] = v.w;
  __syncthreads();
  u16 o4[4];
  o4[0] = f2bf(st[tr][tc4 + 0]); o4[1] = f2bf(st[tr][tc4 + 1]);
  o4[2] = f2bf(st[tr][tc4 + 2]); o4[3] = f2bf(st[tr][tc4 + 3]);
  *(uint2*)(D + (size_t)(n0 + tr) * ds + co + k0 + tc4) = *(uint2*)o4;
}

// ================= combo: Wcomb GEMM | Wcomb2 GEMM | hist, one launch =================
// grid (4, 36): y<12 Wcomb (x<3), y in [12,20) Wcomb2, y in [20,36) hist
__global__ __launch_bounds__(256) void k_combo(const u16* __restrict__ qkvT,
                                               const u16* __restrict__ W1K,
                                               u16* __restrict__ Wcomb,
                                               const u16* __restrict__ fw1T,
                                               const u16* __restrict__ woK,
                                               u16* __restrict__ Wcomb2,
                                               const int* __restrict__ coords,
                                               u32* __restrict__ cnt) {
  int y = blockIdx.y;
  if (y >= 20) {  // hist
    int n = ((y - 20) * 4 + blockIdx.x) * 256 + threadIdx.x;
    int c = coords[n * 3] * 128 + coords[n * 3 + 1];
    atomicAdd(&cnt[c], 1u);
    return;
  }
  const u16 *A, *WT; u16* C; int K, N, bm, bn;
  if (y < 12) {
    if (blockIdx.x >= 3) return;
    A = qkvT; WT = W1K; C = Wcomb; K = 256; N = 192;
    bm = y * 64; bn = blockIdx.x * 64;
  } else {
    A = fw1T; WT = woK; C = Wcomb2; K = 256; N = 256;
    bm = (y - 12) * 64; bn = blockIdx.x * 64;
  }
  __shared__ __align__(16) char smem[16384];
  u16* AsB = (u16*)smem;            // [2][64*32]
  u16* BsB = AsB + 2 * 64 * 32;     // [2][64*32]
  u16* tile = (u16*)smem;           // [64][72] epilogue reuse
  const int tid = threadIdx.x;
  const int wave = tid >> 6, lane = tid & 63;
  const int wr = (wave >> 1) * 32, wc = (wave & 1) * 32;
  const int fr = lane & 15, fk = (lane >> 4) * 8, rq = (lane >> 4) * 4;
  const int grow = tid >> 2, gko = (tid & 3) * 8;

  f32x4 acc[2][2];
#pragma unroll
  for (int i = 0; i < 2; i++)
#pragma unroll
    for (int j = 0; j < 2; j++)
#pragma unroll
      for (int r = 0; r < 4; r++) acc[i][j][r] = 0.f;

  for (int k0 = 0; k0 < K; k0 += 64) {
#pragma unroll
    for (int h = 0; h < 2; h++) {
      gll16(A + (size_t)(bm + grow) * K + k0 + h * 32 + gko, AsB + h * 2048 + tid * 8);
      gll16(WT + (size_t)(bn + grow) * K + k0 + h * 32 + gko, BsB + h * 2048 + tid * 8);
    }
    __syncthreads();
#pragma unroll
    for (int h = 0; h < 2; h++) {
      short8 af[2], bg[2];
#pragma unroll
      for (int i = 0; i < 2; i++)
        af[i] = *(const short8*)&AsB[h * 2048 + (wr + i * 16 + fr) * 32 + fk];
#pragma unroll
      for (int j = 0; j < 2; j++)
        bg[j] = *(const short8*)&BsB[h * 2048 + (wc + j * 16 + fr) * 32 + fk];
#pragma unroll
      for (int i = 0; i < 2; i++)
#pragma unroll
        for (int j = 0; j < 2; j++)
          acc[i][j] = __builtin_amdgcn_mfma_f32_16x16x32_bf16(af[i], bg[j], acc[i][j], 0, 0, 0);
    }
    __syncthreads();
  }
#pragma unroll
  for (int j = 0; j < 2; j++) {
    int ccl = wc + j * 16 + fr;
#pragma unroll
    for (int i = 0; i < 2; i++) {
      int rl = wr + i * 16 + rq;
#pragma unroll
      for (int r = 0; r < 4; r++) tile[(rl + r) * 72 + ccl] = f2bf(acc[i][j][r]);
    }
  }
  __syncthreads();
#pragma unroll
  for (int t = 0; t < 2; t++) {
    int idx = t * 256 + tid;
    int row = idx >> 3, c8 = (idx & 7) * 8;
    *(uint4*)(C + (size_t)(bm + row) * N + bn + c8) = *(const uint4*)&tile[row * 72 + c8];
  }
}

// ================= scatter with fused full-prefix scan (redundant per block) =================
__global__ __launch_bounds__(256) void k_scatter(const int* __restrict__ coords,
                                                 const u32* __restrict__ cnt,
                                                 u32* __restrict__ startb,
                                                 u32* __restrict__ cursor,
                                                 u32* __restrict__ pts) {
  __shared__ u32 sb[16384];   // 64 KB: full exclusive prefix
  __shared__ u32 wsum[4];
  int t = threadIdx.x;
  int lane = t & 63, wid = t >> 6;
  int base = t * 64;
  u32 s = 0;
  for (int i = 0; i < 64; i++) s += cnt[base + i];
  u32 v = s;
#pragma unroll
  for (int off = 1; off < 64; off <<= 1) {
    u32 u = __shfl_up(v, off);
    if (lane >= off) v += u;
  }
  if (lane == 63) wsum[wid] = v;
  __syncthreads();
  u32 woff = 0;
  for (int w2 = 0; w2 < wid; w2++) woff += wsum[w2];
  u32 run = woff + v - s;  // exclusive prefix at cell base
  for (int i = 0; i < 64; i++) { sb[base + i] = run; run += cnt[base + i]; }
  __syncthreads();
  // strip-write this block's 256 cells to global startb (for later select)
  startb[blockIdx.x * 256 + t] = sb[blockIdx.x * 256 + t];
  // scatter this block's points using LDS prefix
  int n = blockIdx.x * 256 + t;
  int x = coords[n * 3], y = coords[n * 3 + 1], z = coords[n * 3 + 2];
  int c = x * 128 + y;
  u32 slot = atomicAdd(&cursor[c], 1u);
  pts[sb[c] + slot] = ((u32)z << 14) | (u32)n;  // z:7b | idx:14b
}

// ================= bf16 MFMA GEMM (h-pair loop) + optional fused select =================
// C = A(MxK,lda) @ WT(NxK)^T -> Cout(ldc). SEL: blocks with y >= M/BM run neighbor-select.
template <int BM, int BN, int ACT, bool SEL>
__global__ __launch_bounds__(256) void k_mgemm(
    const u16* __restrict__ A, const u16* __restrict__ WT,
    const float* __restrict__ bias,
    u16* __restrict__ Cout,
    int M, int K, int N, int lda, int ldc,
    const int* __restrict__ coords,
    const u32* __restrict__ startb,
    const u32* __restrict__ cnt,
    const u32* __restrict__ pts,
    int* __restrict__ idxo) {
  if (SEL && (int)blockIdx.y >= M / BM) {
    // ---- neighbor select, cell-sorted order ----
    int sb = ((int)blockIdx.y - M / BM) * gridDim.x + blockIdx.x;
    if (sb >= 64) return;
    int gid = sb * 256 + threadIdx.x;
    u32 pk = pts[gid];
    int n = (int)(pk & 16383u);
    int z = (int)(pk >> 14);
    int x = coords[n * 3], y = coords[n * 3 + 1];
    u32 best[16];
#pragma unroll
    for (int j = 0; j < 16; j++) best[j] = 0xFFFFFFFFu;
    const int dxs[13] = {0, -1, 1, 0, 0, -2, 2, 0, 0, -1, -1, 1, 1};
    const int dys[13] = {0, 0, 0, -1, 1, 0, 0, -2, 2, -1, 1, -1, 1};
    const int dbs[13] = {0, 1, 1, 1, 1, 2, 2, 2, 2, 2, 2, 2, 2};
#pragma unroll
    for (int t = 0; t < 13; t++) {
      int xx = x + dxs[t], yy = y + dys[t];
      if (xx < 0 || xx > 127 || yy < 0 || yy > 127) continue;
      int c = xx * 128 + yy;
      u32 s0 = startb[c], e0 = s0 + cnt[c];
      for (u32 i = s0; i < e0; ++i) {
        u32 p = pts[i];
        int zq = (int)(p >> 14);
        int id = (int)(p & 16383u);
        int az = z - zq; az = az < 0 ? -az : az;
        int dd = dbs[t] + az;
        u32 key = (dd <= 2) ? (((u32)dd << 14) | (u32)id) : 0xFFFFFFFFu;
#pragma unroll
        for (int j = 0; j < 16; j++) {
          u32 lo = min(best[j], key);
          u32 hi = max(best[j], key);
          best[j] = lo; key = hi;
        }
      }
    }
#pragma unroll
    for (int j = 0; j < 16; j++)
      idxo[gid * 16 + j] = (best[j] == 0xFFFFFFFFu) ? -1 : (int)(best[j] & 16383u);
    return;
  }

  constexpr int FM = BM / 32, FN = BN / 32;
  constexpr int RA = BM / 64, RB = BN / 64;
  constexpr int BNP = BN + 8;
  constexpr int STAGE = (BM + BN) * 128;
  constexpr int TILEB = BM * BNP * 2;
  constexpr int SMEMB = STAGE > TILEB ? STAGE : TILEB;
  __shared__ __align__(16) char smem[SMEMB];
  u16* AsB = (u16*)smem;
  u16* BsB = AsB + 2 * BM * 32;
  u16* tile = (u16*)smem;
  const int tid = threadIdx.x;
  const int wave = tid >> 6, lane = tid & 63;
  const int bm = blockIdx.y * BM, bn = blockIdx.x * BN;
  const int wr = (wave >> 1) * (BM / 2), wc = (wave & 1) * (BN / 2);
  const int fr = lane & 15, fk = (lane >> 4) * 8, rq = (lane >> 4) * 4;

  f32x4 acc[FM][FN];
#pragma unroll
  for (int i = 0; i < FM; i++)
#pragma unroll
    for (int j = 0; j < FN; j++)
#pragma unroll
      for (int r = 0; r < 4; r++) acc[i][j][r] = 0.f;

  for (int k0 = 0; k0 < K; k0 += 64) {
#pragma unroll
    for (int h = 0; h < 2; h++) {
#pragma unroll
      for (int r = 0; r < RA; r++) {
        int g2 = r * 256 + tid;
        gll16(A + (size_t)(bm + (g2 >> 2)) * lda + k0 + h * 32 + (g2 & 3) * 8,
              AsB + h * BM * 32 + g2 * 8);
      }
#pragma unroll
      for (int r = 0; r < RB; r++) {
        int g2 = r * 256 + tid;
        gll16(WT + (size_t)(bn + (g2 >> 2)) * K + k0 + h * 32 + (g2 & 3) * 8,
              BsB + h * BN * 32 + g2 * 8);
      }
    }
    __syncthreads();
#pragma unroll
    for (int h = 0; h < 2; h++) {
      short8 af[FM], bg[FN];
#pragma unroll
      for (int i = 0; i < FM; i++)
        af[i] = *(const short8*)&AsB[h * BM * 32 + (wr + i * 16 + fr) * 32 + fk];
#pragma unroll
      for (int j = 0; j < FN; j++)
        bg[j] = *(const short8*)&BsB[h * BN * 32 + (wc + j * 16 + fr) * 32 + fk];
#pragma unroll
      for (int i = 0; i < FM; i++)
#pragma unroll
        for (int j = 0; j < FN; j++)
          acc[i][j] = __builtin_amdgcn_mfma_f32_16x16x32_bf16(af[i], bg[j], acc[i][j], 0, 0, 0);
    }
    __syncthreads();
  }

#pragma unroll
  for (int j = 0; j < FN; j++) {
    int ccl = wc + j * 16 + fr;
    float bval = bias ? bias[bn + ccl] : 0.f;
#pragma unroll
    for (int i = 0; i < FM; i++) {
      int rl = wr + i * 16 + rq;
#pragma unroll
      for (int r = 0; r < 4; r++) {
        float v = acc[i][j][r] + bval;
        if (ACT) v = fmaxf(v, 0.f);
        tile[(rl + r) * BNP + ccl] = f2bf(v);
      }
    }
  }
  __syncthreads();
  constexpr int RPW = BN / 8;
  constexpr int PT = BM * BN / 8 / 256;
#pragma unroll
  for (int t = 0; t < PT; t++) {
    int idx = t * 256 + tid;
    int row = idx / RPW, c8 = (idx % RPW) * 8;
    *(uint4*)(Cout + (size_t)(bm + row) * ldc + bn + c8) =
        *(const uint4*)&tile[row * BNP + c8];
  }
}

// ================= attention -> AH[:,0:256] (stride 768), cell-sorted =================
__global__ __launch_bounds__(256) void k_attn(const u16* __restrict__ QKV,
                                              const u32* __restrict__ pts,
                                              const int* __restrict__ idx,
                                              const float* __restrict__ bq,
                                              const float* __restrict__ bk,
                                              const float* __restrict__ bv,
                                              u16* __restrict__ outp) {
  int gid = blockIdx.x * 256 + threadIdx.x;
  int s4 = gid >> 3;  // sorted position
  int n = (int)(pts[s4] & 16383u), h = gid & 7;
  const int* ip = idx + s4 * 16;
  const int hb = h * 32;
  float q[32];
  {
    int i0 = ip[0];
    const u16* qp = QKV + (size_t)i0 * 768 + hb;
#pragma unroll
    for (int j = 0; j < 32; j += 8) ldbf8(qp + j, &q[j]);
#pragma unroll
    for (int j = 0; j < 32; j++) q[j] += bq[hb + j];
  }
  float qbk = 0.f;
#pragma unroll
  for (int j = 0; j < 32; j++) qbk += q[j] * bk[hb + j];
  float s[16]; int ii[16];
#pragma unroll
  for (int m = 0; m < 16; m++) {
    int i = ip[m]; ii[m] = i;
    float d = qbk;
    if (i >= 0) {
      const u16* kp = QKV + (size_t)i * 768 + 256 + hb;
      float kv[32];
#pragma unroll
      for (int j = 0; j < 32; j += 8) ldbf8(kp + j, &kv[j]);
#pragma unroll
      for (int j = 0; j < 32; j++) d += q[j] * kv[j];
    }
    s[m] = d * 0.17677669529663689f;  // 1/sqrt(32)
  }
  float mx = s[0];
#pragma unroll
  for (int m = 1; m < 16; m++) mx = fmaxf(mx, s[m]);
  float sum = 0.f;
#pragma unroll
  for (int m = 0; m < 16; m++) { s[m] = __expf(s[m] - mx); sum += s[m]; }
  float inv = 1.f / sum;
  float o[32];
#pragma unroll
  for (int j = 0; j < 32; j++) o[j] = 0.f;
#pragma unroll
  for (int m = 0; m < 16; m++) {
    if (ii[m] >= 0) {
      const u16* vp = QKV + (size_t)ii[m] * 768 + 512 + hb;
      float vv[32];
#pragma unroll
      for (int j = 0; j < 32; j += 8) ldbf8(vp + j, &vv[j]);
#pragma unroll
      for (int j = 0; j < 32; j++) o[j] += s[m] * vv[j];
    }
  }
  u16* op = outp + (size_t)n * 768 + hb;  // AH stride 768
#pragma unroll
  for (int j = 0; j < 32; j += 8) {
    u16 tmp[8];
#pragma unroll
    for (int jj = 0; jj < 8; jj++) tmp[jj] = f2bf(o[j + jj] * inv + bv[hb + j + jj]);
    *(uint4*)(op + j) = *(uint4*)tmp;
  }
}

// ================= fused: ffn2(K=768) + LN + f GEMM(K=320) + BN stats =================
// Block owns 64 rows. Phase 1: x = AH @ WTBIG^T + (bo+fb2). Phase 2: LN -> y (bf16, LDS).
// Phase 3: f = [y | feats] @ W2f^T + bbf -> fB + column stats atomics.
__global__ __launch_bounds__(256) void k_ffn2f(const u16* __restrict__ AH,
                                               const u16* __restrict__ WTBIG,
                                               const float* __restrict__ bo,
                                               const float* __restrict__ fb2,
                                               const float* __restrict__ g,
                                               const float* __restrict__ b,
                                               const u16* __restrict__ A2,
                                               const u16* __restrict__ W2f,
                                               const float* __restrict__ bbf,
                                               float* __restrict__ fB,
                                               float* __restrict__ pS,
                                               float* __restrict__ pQ) {
  constexpr int BM = 64, BN = 256, FM = 2, FN = 8;
  constexpr int ADP2 = 328;                       // A-tile stride (u16): 256 y + 64 feats + 8 pad
  __shared__ __align__(16) char smem[BM * ADP2 * 2];  // 41984 B >= 40960 staging
  __shared__ __align__(16) u16 Bs2[2][2048];      // W2f staging (phase 3)
  __shared__ float lnS[64][2], lnQ[64][2];
  __shared__ float colS[64][2], colQ[64][2];
  u16* AsB = (u16*)smem;                 // phase 1: [2][64*32]
  u16* BsB = AsB + 2 * BM * 32;          // phase 1: [2][256*32]
  u16* aT  = (u16*)smem;                 // phase 2/3: [64][ADP2] = [y | feats]
  const int tid = threadIdx.x;
  const int wave = tid >> 6, lane = tid & 63;
  const int bm = blockIdx.x * BM;
  const int wr = (wave >> 1) * 32, wc = (wave & 1) * 128;
  const int fr = lane & 15, fk = (lane >> 4) * 8, rq = (lane >> 4) * 4;

  // ---------- phase 1: ffn2 GEMM, K=768 ----------
  f32x4 acc[FM][FN];
#pragma unroll
  for (int i = 0; i < FM; i++)
#pragma unroll
    for (int j = 0; j < FN; j++)
#pragma unroll
      for (int r = 0; r < 4; r++) acc[i][j][r] = 0.f;

  for (int k0 = 0; k0 < 768; k0 += 64) {
#pragma unroll
    for (int h = 0; h < 2; h++) {
      {
        int g2 = tid;
        gll16(AH + (size_t)(bm + (g2 >> 2)) * 768 + k0 + h * 32 + (g2 & 3) * 8,
              AsB + h * BM * 32 + g2 * 8);
      }
#pragma unroll
      for (int r = 0; r < 4; r++) {
        int g2 = r * 256 + tid;
        gll16(WTBIG + (size_t)(g2 >> 2) * 768 + k0 + h * 32 + (g2 & 3) * 8,
              BsB + h * BN * 32 + g2 * 8);
      }
    }
    __syncthreads();
#pragma unroll
    for (int h = 0; h < 2; h++) {
      short8 af[FM], bg[FN];
#pragma unroll
      for (int i = 0; i < FM; i++)
        af[i] = *(const short8*)&AsB[h * BM * 32 + (wr + i * 16 + fr) * 32 + fk];
#pragma unroll
      for (int j = 0; j < FN; j++)
        bg[j] = *(const short8*)&BsB[h * BN * 32 + (wc + j * 16 + fr) * 32 + fk];
#pragma unroll
      for (int i = 0; i < FM; i++)
#pragma unroll
        for (int j = 0; j < FN; j++)
          acc[i][j] = __builtin_amdgcn_mfma_f32_16x16x32_bf16(af[i], bg[j], acc[i][j], 0, 0, 0);
    }
    __syncthreads();
  }

  // ---------- phase 2: bias, LN stats, normalize -> y into aT; feats into aT ----------
#pragma unroll
  for (int j = 0; j < FN; j++) {
    int cc = wc + j * 16 + fr;
    float bval = bo[cc] + fb2[cc];
#pragma unroll
    for (int i = 0; i < FM; i++)
#pragma unroll
      for (int r = 0; r < 4; r++) acc[i][j][r] += bval;
  }
#pragma unroll
  for (int i = 0; i < FM; i++) {
#pragma unroll
    for (int r = 0; r < 4; r++) {
      float sm = 0.f, sq = 0.f;
#pragma unroll
      for (int j = 0; j < FN; j++) { float t = acc[i][j][r]; sm += t; sq += t * t; }
#pragma unroll
      for (int off = 1; off < 16; off <<= 1) {
        sm += __shfl_xor(sm, off);
        sq += __shfl_xor(sq, off);
      }
      if (fr == 0) {
        int row = wr + i * 16 + rq + r;
        lnS[row][wave & 1] = sm;
        lnQ[row][wave & 1] = sq;
      }
    }
  }
  __syncthreads();   // lnS/lnQ ready; phase-1 staging fully consumed -> aT may overwrite
#pragma unroll
  for (int i = 0; i < FM; i++) {
#pragma unroll
    for (int r = 0; r < 4; r++) {
      int row = wr + i * 16 + rq + r;
      float sm = lnS[row][0] + lnS[row][1];
      float sq = lnQ[row][0] + lnQ[row][1];
      float mu = sm * (1.f / 256.f);
      float var = sq * (1.f / 256.f) - mu * mu;
      float rstd = rsqrtf(var + kEPS);
#pragma unroll
      for (int j = 0; j < FN; j++) {
        int cc = wc + j * 16 + fr;
        float val = (acc[i][j][r] - mu) * rstd * g[cc] + b[cc];
        aT[row * ADP2 + cc] = f2bf(val);
      }
    }
  }
  // feats: A2[:,256:320] -> aT[:,256:320]  (64 rows x 8 uint4/row = 512 loads)
#pragma unroll
  for (int t = 0; t < 2; t++) {
    int idx = t * 256 + tid;
    int row = idx >> 3, c8 = (idx & 7) * 8;
    *(uint4*)&aT[row * ADP2 + 256 + c8] =
        *(const uint4*)(A2 + (size_t)(bm + row) * 320 + 256 + c8);
  }
  __syncthreads();

  // ---------- phase 3: f GEMM K=320, A from aT (LDS), B = W2f staged ----------
  const int wr3 = (wave >> 1) * 32, wc3 = (wave & 1) * 32;
  const int grow = tid >> 2, gko = (tid & 3) * 8;
  f32x4 acc2[2][2];
#pragma unroll
  for (int i = 0; i < 2; i++)
#pragma unroll
    for (int j = 0; j < 2; j++)
#pragma unroll
      for (int r = 0; r < 4; r++) acc2[i][j][r] = 0.f;
  for (int k0 = 0; k0 < 320; k0 += 64) {
#pragma unroll
    for (int h = 0; h < 2; h++)
      gll16(W2f + (size_t)grow * 320 + k0 + h * 32 + gko, Bs2[h] + tid * 8);
    __syncthreads();
#pragma unroll
    for (int h = 0; h < 2; h++) {
      short8 af[2], bg[2];
#pragma unroll
      for (int i = 0; i < 2; i++)
        af[i] = *(const short8*)&aT[(wr3 + i * 16 + fr) * ADP2 + k0 + h * 32 + fk];
#pragma unroll
      for (int j = 0; j < 2; j++)
        bg[j] = *(const short8*)&Bs2[h][(wc3 + j * 16 + fr) * 32 + fk];
#pragma unroll
      for (int i = 0; i < 2; i++)
#pragma unroll
        for (int j = 0; j < 2; j++)
          acc2[i][j] = __builtin_amdgcn_mfma_f32_16x16x32_bf16(af[i], bg[j], acc2[i][j], 0, 0, 0);
    }
    __syncthreads();
  }
  // bias + fB write + column stats
  float cS[2] = {0.f, 0.f}, cQ[2] = {0.f, 0.f};
#pragma unroll
  for (int j = 0; j < 2; j++) {
    int col = wc3 + j * 16 + fr;
    float bv = bbf[col];
#pragma unroll
    for (int i = 0; i < 2; i++) {
      int rbase = bm + wr3 + i * 16 + rq;
#pragma unroll
      for (int r = 0; r < 4; r++) {
        float v = acc2[i][j][r] + bv;
        fB[(size_t)(rbase + r) * 64 + col] = v;
        cS[j] += v; cQ[j] += v * v;
      }
    }
  }
#pragma unroll
  for (int off = 16; off < 64; off <<= 1) {
#pragma unroll
    for (int j = 0; j < 2; j++) {
      cS[j] += __shfl_xor(cS[j], off);
      cQ[j] += __shfl_xor(cQ[j], off);
    }
  }
  if ((lane >> 4) == 0) {
#pragma unroll
    for (int j = 0; j < 2; j++) {
      colS[wc3 + j * 16 + fr][wave >> 1] = cS[j];
      colQ[wc3 + j * 16 + fr][wave >> 1] = cQ[j];
    }
  }
  __syncthreads();
  if (tid < 64) {
    atomicAdd(&pS[tid], colS[tid][0] + colS[tid][1]);
    atomicAdd(&pQ[tid], colQ[tid][0] + colQ[tid][1]);
  }
}

// ================= BN finalize (per-block recompute) + apply + relu =================
__global__ __launch_bounds__(256) void k_bnapply(const float* __restrict__ f,
                                                 const float* __restrict__ pS,
                                                 const float* __restrict__ pQ,
                                                 const float* __restrict__ g,
                                                 const float* __restrict__ b,
                                                 float* __restrict__ out) {
  __shared__ float cf_s[64], sh_s[64];
  if (threadIdx.x < 64) {
    int c = threadIdx.x;
    float S = pS[c], Q = pQ[c];
    float m = S * (1.f / 16384.f);
    float var = Q * (1.f / 16384.f) - m * m;
    float cf = rsqrtf(var + kEPS) * g[c];
    cf_s[c] = cf;
    sh_s[c] = b[c] - m * cf;
  }
  __syncthreads();
  int gid = blockIdx.x * 256 + threadIdx.x;
  int e = gid * 4, col = e & 63;
  float4 v = *(const float4*)(f + e);
  float4 cf = *(const float4*)(cf_s + col);
  float4 sh = *(const float4*)(sh_s + col);
  float4 o;
  o.x = fmaxf(v.x * cf.x + sh.x, 0.f);
  o.y = fmaxf(v.y * cf.y + sh.y, 0.f);
  o.z = fmaxf(v.z * cf.z + sh.z, 0.f);
  o.w = fmaxf(v.w * cf.w + sh.w, 0.f);
  *(float4*)(out + e) = o;
}

// ================= launch =================
extern "C" void kernel_launch(void* const* d_in, const int* in_sizes, int n_in,
                              void* d_out, int out_size, void* d_ws, size_t ws_size,
                              hipStream_t stream) {
  (void)in_sizes; (void)n_in; (void)out_size; (void)ws_size;
  const int*   coords = (const int*)d_in[0];
  const float* feats  = (const float*)d_in[1];
  const float* pe_w1  = (const float*)d_in[2];
  const float* pe_b1  = (const float*)d_in[3];
  const float* pe_w2  = (const float*)d_in[4];
  const float* pe_b2  = (const float*)d_in[5];
  const float* proj_w = (const float*)d_in[6];
  const float* proj_b = (const float*)d_in[7];
  const float* wq  = (const float*)d_in[8];
  const float* bq  = (const float*)d_in[9];
  const float* wk  = (const float*)d_in[10];
  const float* bk  = (const float*)d_in[11];
  const float* wv  = (const float*)d_in[12];
  const float* bv  = (const float*)d_in[13];
  const float* wo  = (const float*)d_in[14];
  const float* bo  = (const float*)d_in[15];
  const float* fw1 = (const float*)d_in[16];
  const float* fb1 = (const float*)d_in[17];
  const float* fw2 = (const float*)d_in[18];
  const float* fb2 = (const float*)d_in[19];
  const float* lng = (const float*)d_in[20];
  const float* lnb = (const float*)d_in[21];
  const float* uw1 = (const float*)d_in[22];
  const float* ub1 = (const float*)d_in[23];
  const float* uw2 = (const float*)d_in[24];
  const float* ub2 = (const float*)d_in[25];
  const float* bng = (const float*)d_in[26];
  const float* bnb = (const float*)d_in[27];
  float* out = (float*)d_out;

  char* Wc = (char*)d_ws;
  const size_t MB = 1u << 20;
  u16*   A1    = (u16*)(Wc + 0 * MB);    // 6MB
  u16*   QKVb  = (u16*)(Wc + 14 * MB);   // 24MB (14..38)
  u16*   AH    = (u16*)(Wc + 38 * MB);   // 24MB (38..62): [attnOut | h1] stride 768
  u16*   A2    = (u16*)(Wc + 78 * MB);   // 10MB [unused y | feats]
  float* fB    = (float*)(Wc + 0 * MB);  // 4MB over dead A1

  u16* qkvT   = (u16*)(Wc + 88 * MB);    // 768 x 256
  u16* WTBIG  = qkvT + 196608;           // 256 x 768 ([woT | fw2T] rows)
  u16* fw1T   = WTBIG + 196608;          // 512 x 256
  u16* woK    = fw1T + 131072;           // 256 x 256 (row-major cast of wo)
  u16* W1K    = woK + 65536;             // 192 x 256
  u16* W2f    = W1K + 49152;             // 64 x 320
  u16* Wcomb  = W2f + 20480;             // 768 x 192
  u16* Wcomb2 = Wcomb + 147456;          // 512 x 256 (WT layout of wo@fw1)
  float* bbf    = (float*)(Wcomb2 + 131072);  // 64
  float* bcomb  = bbf + 64;              // 768
  float* bcomb2 = bcomb + 768;           // 512

  u32* Z      = (u32*)(Wc + 90 * MB);
  u32* cnt    = Z;                        // 16384  (zeroed)
  u32* cursor = Z + 16384;                // 16384  (zeroed)
  float* pS   = (float*)(Z + 32768);      // 64     (zeroed)
  float* pQ   = (float*)(Z + 32832);      // 64     (zeroed)
  u32* startb = Z + 33280;                // 16384
  u32* pts    = Z + 49664;                // 16384
  int* idxb   = (int*)(Z + 66048);        // N*16 (by sorted position)

  WSet ws;
  ws.s[0] = wq;  ws.d[0] = qkvT;          ws.K[0] = 256; ws.N[0] = 256; ws.dstride[0] = 256; ws.coff[0] = 0;
  ws.s[1] = wk;  ws.d[1] = qkvT + 65536;  ws.K[1] = 256; ws.N[1] = 256; ws.dstride[1] = 256; ws.coff[1] = 0;
  ws.s[2] = wv;  ws.d[2] = qkvT + 131072; ws.K[2] = 256; ws.N[2] = 256; ws.dstride[2] = 256; ws.coff[2] = 0;
  ws.s[3] = wo;  ws.d[3] = WTBIG;         ws.K[3] = 256; ws.N[3] = 256; ws.dstride[3] = 768; ws.coff[3] = 0;
  ws.s[4] = fw1; ws.d[4] = fw1T;          ws.K[4] = 256; ws.N[4] = 512; ws.dstride[4] = 256; ws.coff[4] = 0;
  ws.s[5] = fw2; ws.d[5] = WTBIG;         ws.K[5] = 512; ws.N[5] = 256; ws.dstride[5] = 768; ws.coff[5] = 256;

  // 1. setup
  k_setup<<<dim3(512, 10), 256, 0, stream>>>(ws, Z, proj_b, pe_b2,
                                             uw1, ub1, uw2, ub2, W2f, bbf,
                                             coords, feats, pe_w1, pe_b1, A1, A2,
                                             wq, wk, wv, proj_w, pe_w2, W1K, bcomb,
                                             wo, fw1, bo, fb1, woK, bcomb2);
  // 2. combo: Wcomb GEMM + Wcomb2 GEMM + hist
  k_combo<<<dim3(4, 36), 256, 0, stream>>>(qkvT, W1K, Wcomb, fw1T, woK, Wcomb2,
                                           coords, cnt);
  // 3. scatter (+ fused redundant scan)
  k_scatter<<<64, 256, 0, stream>>>(coords, cnt, startb, cursor, pts);
  // 4. QKV (K=192, N=768) + fused neighbor-select (y >= 128)
  k_mgemm<128, 128, 0, true><<<dim3(6, 139), 256, 0, stream>>>(
      A1, Wcomb, bcomb, QKVb, kN, 192, 768, 192, 768,
      coords, startb, cnt, pts, idxb);
  // 5. attention -> AH[:,0:256]
  k_attn<<<512, 256, 0, stream>>>(QKVb, pts, idxb, bq, bk, bv, AH);
  // 6. h1 = relu(attnOut @ Wcomb2^T + bcomb2) -> AH[:,256:768], K=256, N=512
  k_mgemm<128, 128, 1, false><<<dim3(4, 128), 256, 0, stream>>>(
      AH, Wcomb2, bcomb2, AH + 256, kN, 256, 512, 768, 768,
      nullptr, nullptr, nullptr, nullptr, nullptr);
  // 7. fused: ffn2 + LN + f GEMM + BN stats
  k_ffn2f<<<256, 256, 0, stream>>>(AH, WTBIG, bo, fb2, lng, lnb,
                                   A2, W2f, bbf, fB, pS, pQ);
  // 8. BN finalize (per-block) + apply
  k_bnapply<<<1024, 256, 0, stream>>>(fB, pS, pQ, bng, bnb, out);
}